// Round 5
// baseline (519.971 us; speedup 1.0000x reference)
//
#include <hip/hip_runtime.h>
#include <math.h>

#define T_SEQ 4096
#define CEMB  1024
#define CHEAD 64
#define NB    8

typedef __attribute__((ext_vector_type(8))) short bf8;   // 8 bf16 (4 VGPRs)
typedef __attribute__((ext_vector_type(4))) short s4v;   // 4 bf16 (8B)
typedef __attribute__((ext_vector_type(4))) float f4;    // MFMA C/D

#define MFMA(a, b, c) __builtin_amdgcn_mfma_f32_16x16x32_bf16((a), (b), (c), 0, 0, 0)

__device__ __forceinline__ short f2bf(float f) {
    unsigned int u = __float_as_uint(f);
    u += 0x7fffu + ((u >> 16) & 1u);          // round-to-nearest-even
    return (short)(u >> 16);
}
__device__ __forceinline__ float bf2f(short h) {
    return __uint_as_float(((unsigned int)(unsigned short)h) << 16);
}

// ---------------------------------------------------------------------------
// Kernel 0: W -> hi/lo bf16 split, chunk-major XOR-swizzled layout:
// Wp[c>>5][2m+hl][h][ (c&31) ^ (((h>>1)&3)<<3) ]
// ---------------------------------------------------------------------------
__global__ __launch_bounds__(256) void wsplit_kernel(
    const float* __restrict__ Wk, const float* __restrict__ Wq,
    const float* __restrict__ Wv, short* __restrict__ Wp)
{
    int id = blockIdx.x * 256 + threadIdx.x;       // exactly 3*65536 threads
    int m = id >> 16;
    int rem = id & 65535;
    int c = rem >> 6, h = rem & 63;
    const float* W = (m == 0) ? Wq : (m == 1) ? Wk : Wv;
    float f = W[c * 64 + h];
    short hi = f2bf(f);
    short lo = f2bf(f - bf2f(hi));
    int cs = (c & 31) ^ (((h >> 1) & 3) << 3);
    size_t base = ((size_t)(c >> 5) * 6) * 2048 + (size_t)h * 32 + cs;
    Wp[base + (size_t)(2 * m) * 2048]     = hi;
    Wp[base + (size_t)(2 * m + 1) * 2048] = lo;
}

// ---------------------------------------------------------------------------
// Kernel 1: QKV projection, 2-term split (xh*Wh + xh*Wl; x-lo dropped —
// consistent Q,K buffers make this a pure weight-redistribution error).
// 256 thr = 4 waves x 16 rows; 64-row tiles; grid 512; dbuf W via
// global_load_lds; LDS 48KB.
// ---------------------------------------------------------------------------
__global__ __launch_bounds__(256) void proj_kernel(
    const float* __restrict__ x, const short* __restrict__ Wp,
    short* __restrict__ Qhi, short* __restrict__ Qlo,
    short* __restrict__ Khi, short* __restrict__ Klo,
    short* __restrict__ VThi, short* __restrict__ VTlo)
{
    __shared__ short wbuf[2][12288];               // 2 x 24KB
    const int tid = threadIdx.x;
    const int lane = tid & 63, w = tid >> 6;       // w in 0..3
    const int l15 = lane & 15, lg = lane >> 4;
    const int row0 = blockIdx.x * 64;

    f4 acc[3][4] = {};
    float4 xrA[2], xrB[2];

    auto stage = [&](int c, int buf) {
        const short* src = Wp + (size_t)c * 12288 + tid * 8;
        #pragma unroll
        for (int p = 0; p < 6; ++p) {
            __builtin_amdgcn_global_load_lds(
                (const __attribute__((address_space(1))) void*)(src + p * 2048),
                (__attribute__((address_space(3))) void*)&wbuf[buf][tid * 8 + p * 2048],
                16, 0, 0);
        }
    };
    auto xload = [&](int c, float4 (&xr)[2]) {
        const float* px = x + (size_t)(row0 + 16 * w + l15) * CEMB + c * 32 + lg * 8;
        xr[0] = *reinterpret_cast<const float4*>(px);
        xr[1] = *reinterpret_cast<const float4*>(px + 4);
    };
    const int swz = ((l15 >> 1) & 3) << 3;
    auto compute = [&](const float4 (&xr)[2], int buf) {
        bf8 xh;
        #pragma unroll
        for (int hv = 0; hv < 2; ++hv) {
            const float* fp = reinterpret_cast<const float*>(&xr[hv]);
            #pragma unroll
            for (int e = 0; e < 4; ++e) xh[hv * 4 + e] = f2bf(fp[e]);
        }
        #pragma unroll
        for (int m = 0; m < 3; ++m)
            #pragma unroll
            for (int hf = 0; hf < 4; ++hf) {
                int h = 16 * hf + l15;
                const short* bp = &wbuf[buf][(2 * m) * 2048 + h * 32 + ((lg << 3) ^ swz)];
                bf8 wh = *reinterpret_cast<const bf8*>(bp);
                bf8 wl = *reinterpret_cast<const bf8*>(bp + 2048);
                acc[m][hf] = MFMA(xh, wh, acc[m][hf]);
                acc[m][hf] = MFMA(xh, wl, acc[m][hf]);
            }
    };

    stage(0, 0);
    xload(0, xrA);
    __syncthreads();
    for (int c = 0; c < 32; c += 2) {
        stage(c + 1, 1);
        xload(c + 1, xrB);
        compute(xrA, 0);
        __syncthreads();
        if (c + 2 < 32) { stage(c + 2, 0); xload(c + 2, xrA); }
        compute(xrB, 1);
        __syncthreads();
    }

    #pragma unroll
    for (int hf = 0; hf < 4; ++hf) {
        int hcol = 16 * hf + l15;
        int qb = row0 + 16 * w + lg * 4;              // + r
        #pragma unroll
        for (int r = 0; r < 4; ++r) {
            float fq = acc[0][hf][r];
            short hq = f2bf(fq);
            Qhi[(size_t)(qb + r) * 64 + hcol] = hq;
            Qlo[(size_t)(qb + r) * 64 + hcol] = f2bf(fq - bf2f(hq));
            float fk = acc[1][hf][r];
            short hk = f2bf(fk);
            Khi[(size_t)(qb + r) * 64 + hcol] = hk;
            Klo[(size_t)(qb + r) * 64 + hcol] = f2bf(fk - bf2f(hk));
        }
        int bb = qb >> 12, t0 = qb & 4095;
        s4v vh, vl;
        #pragma unroll
        for (int r = 0; r < 4; ++r) {
            float fv = acc[2][hf][r];
            vh[r] = f2bf(fv);
            vl[r] = f2bf(fv - bf2f(vh[r]));
        }
        *reinterpret_cast<s4v*>(&VThi[((size_t)bb * 64 + hcol) * T_SEQ + t0]) = vh;
        *reinterpret_cast<s4v*>(&VTlo[((size_t)bb * 64 + hcol) * T_SEQ + t0]) = vl;
    }
}

// ---------------------------------------------------------------------------
// Kernel 2: column denominators, hi*hi only (d is a long sum; 0.3% per-exp
// error averages out).  grid (64 ktiles, 4 qsplits, B).
// ---------------------------------------------------------------------------
__global__ __launch_bounds__(256, 4) void colsum_kernel(
    const short* __restrict__ Qhi, const short* __restrict__ Khi,
    float* __restrict__ Dp)
{
    __shared__ float red[4][64];
    const int tid = threadIdx.x;
    const int lane = tid & 63, w = tid >> 6;
    const int l15 = lane & 15, lg = lane >> 4;
    const int k0 = blockIdx.x * 64;
    const int qs = blockIdx.y, b = blockIdx.z;
    const size_t bT = (size_t)b * T_SEQ;

    bf8 kbh[4][2];
    #pragma unroll
    for (int kf = 0; kf < 4; ++kf)
        #pragma unroll
        for (int dc = 0; dc < 2; ++dc)
            kbh[kf][dc] = *reinterpret_cast<const bf8*>(
                Khi + (bT + k0 + 16 * kf + l15) * 64 + dc * 32 + lg * 8);
    float csum[4] = {0.f, 0.f, 0.f, 0.f};

    for (int q0 = k0 + qs * 128; q0 < T_SEQ; q0 += 512) {
        bf8 qah[2][2];
        #pragma unroll
        for (int qf = 0; qf < 2; ++qf)
            #pragma unroll
            for (int dc = 0; dc < 2; ++dc) {
                int row = q0 + w * 32 + 16 * qf + l15;
                row = row < T_SEQ ? row : T_SEQ - 1;
                qah[qf][dc] = *reinterpret_cast<const bf8*>(
                    Qhi + (bT + row) * 64 + dc * 32 + lg * 8);
            }
        f4 s[2][4] = {};
        #pragma unroll
        for (int dc = 0; dc < 2; ++dc)
            #pragma unroll
            for (int qf = 0; qf < 2; ++qf)
                #pragma unroll
                for (int kf = 0; kf < 4; ++kf)
                    s[qf][kf] = MFMA(qah[qf][dc], kbh[kf][dc], s[qf][kf]);
        #pragma unroll
        for (int qf = 0; qf < 2; ++qf)
            #pragma unroll
            for (int kf = 0; kf < 4; ++kf)
                #pragma unroll
                for (int r = 0; r < 4; ++r) {
                    int q = q0 + w * 32 + 16 * qf + lg * 4 + r;
                    int kc = k0 + 16 * kf + l15;
                    if (q >= kc && q < T_SEQ)
                        csum[kf] += __expf(s[qf][kf][r] * 0.125f);
                }
    }
    #pragma unroll
    for (int kf = 0; kf < 4; ++kf) {
        csum[kf] += __shfl_xor(csum[kf], 16);
        csum[kf] += __shfl_xor(csum[kf], 32);
    }
    if (lg == 0) {
        #pragma unroll
        for (int kf = 0; kf < 4; ++kf) red[w][16 * kf + l15] = csum[kf];
    }
    __syncthreads();
    if (tid < 64) {
        float d = red[0][tid] + red[1][tid] + red[2][tid] + red[3][tid];
        Dp[((size_t)qs * NB + b) * T_SEQ + k0 + tid] = d;
    }
}

// ---------------------------------------------------------------------------
// Kernel 3: Dinv = 1 / (sum of 4 Dp partials)
// ---------------------------------------------------------------------------
__global__ __launch_bounds__(256) void dinv_kernel(
    const float* __restrict__ Dp, float* __restrict__ Dinv)
{
    int i = blockIdx.x * 256 + threadIdx.x;        // 32768 threads
    const int S = NB * T_SEQ;
    float d = Dp[i] + Dp[S + i] + Dp[2 * S + i] + Dp[3 * S + i];
    Dinv[i] = 1.0f / d;
}

// ---------------------------------------------------------------------------
// Kernel 4: O = (exp(S)/d) @ V.  64-row q-tiles, 4 waves x 16 rows,
// 2-way k-split, grid 1024 (4 blocks/CU).  QK^T 3-term; PV 2-term
// (P hi-only through 2KB/wave swizzled LDS; V hi+lo).  No barriers in loop.
// ---------------------------------------------------------------------------
__global__ __launch_bounds__(256, 4) void out_kernel(
    const short* __restrict__ Qhi, const short* __restrict__ Qlo,
    const short* __restrict__ Khi, const short* __restrict__ Klo,
    const short* __restrict__ VThi, const short* __restrict__ VTlo,
    const float* __restrict__ Dinv,
    float* __restrict__ out, float* __restrict__ Op1)
{
    __shared__ short pt[4][1024];     // [wave][16 q rows x 64 k] hi-only P
    const int tid = threadIdx.x;
    const int lane = tid & 63, w = tid >> 6;
    const int l15 = lane & 15, lg = lane >> 4;
    const int bx = blockIdx.x;
    const int ks = bx >> 9;
    const int rem = bx & 511;
    const int b = rem >> 6;
    const int ii = rem & 63;
    const int qt = ks ? 63 - ii : ii;              // pairing for balance
    const int q0 = qt * 64;
    const size_t bT = (size_t)b * T_SEQ;
    short* ptw = pt[w];
    const int swz = (l15 & 7) << 3;

    bf8 qh[2], ql[2];                 // persistent Q frags (16 rows/wave)
    #pragma unroll
    for (int dc = 0; dc < 2; ++dc) {
        size_t o = (bT + q0 + 16 * w + l15) * 64 + dc * 32 + lg * 8;
        qh[dc] = *reinterpret_cast<const bf8*>(Qhi + o);
        ql[dc] = *reinterpret_cast<const bf8*>(Qlo + o);
    }
    f4 oacc[4] = {};
    const int qv = q0 + 16 * w + l15;

    for (int k0 = ks * 64; k0 < q0 + 64; k0 += 128) {
        // --- S^T = K · Q^T (3-term split) ---
        f4 st[4] = {};
        #pragma unroll
        for (int dc = 0; dc < 2; ++dc) {
            bf8 kh[4], kl[4];
            #pragma unroll
            for (int kf = 0; kf < 4; ++kf) {
                size_t o = (bT + k0 + 16 * kf + l15) * 64 + dc * 32 + lg * 8;
                kh[kf] = *reinterpret_cast<const bf8*>(Khi + o);
                kl[kf] = *reinterpret_cast<const bf8*>(Klo + o);
            }
            #pragma unroll
            for (int kf = 0; kf < 4; ++kf) {
                st[kf] = MFMA(kh[kf], qh[dc], st[kf]);
                st[kf] = MFMA(kh[kf], ql[dc], st[kf]);
                st[kf] = MFMA(kl[kf], qh[dc], st[kf]);
            }
        }
        // --- P = exp(S)/d (hi-only), per-wave swizzled LDS transpose ---
        #pragma unroll
        for (int kf = 0; kf < 4; ++kf) {
            float4 di = *reinterpret_cast<const float4*>(
                Dinv + b * T_SEQ + k0 + 16 * kf + 4 * lg);
            const float* dip = reinterpret_cast<const float*>(&di);
            unsigned short hb[4];
            #pragma unroll
            for (int r = 0; r < 4; ++r) {
                int kg = k0 + 16 * kf + 4 * lg + r;
                float p = (qv >= kg) ? __expf(st[kf][r] * 0.125f) * dip[r] : 0.f;
                hb[r] = (unsigned short)f2bf(p);
            }
            int sidx = l15 * 64 + (((16 * kf + 4 * lg) ^ swz));
            *reinterpret_cast<int2*>(&ptw[sidx]) = make_int2(
                (int)((unsigned)hb[0] | ((unsigned)hb[1] << 16)),
                (int)((unsigned)hb[2] | ((unsigned)hb[3] << 16)));
        }
        // --- PV: O += P · V (P hi x (V hi + V lo)) ---
        #pragma unroll
        for (int kb = 0; kb < 2; ++kb) {
            bf8 vh[4], vl[4];
            #pragma unroll
            for (int hf = 0; hf < 4; ++hf) {
                size_t o = ((size_t)b * 64 + 16 * hf + l15) * T_SEQ
                         + k0 + 32 * kb + 8 * lg;
                vh[hf] = *reinterpret_cast<const bf8*>(VThi + o);
                vl[hf] = *reinterpret_cast<const bf8*>(VTlo + o);
            }
            int ridx = l15 * 64 + (((32 * kb + 8 * lg) ^ swz));
            bf8 pa = *reinterpret_cast<const bf8*>(&ptw[ridx]);
            #pragma unroll
            for (int hf = 0; hf < 4; ++hf) {
                oacc[hf] = MFMA(pa, vh[hf], oacc[hf]);
                oacc[hf] = MFMA(pa, vl[hf], oacc[hf]);
            }
        }
    }
    float* dst = ks ? Op1 : out;
    #pragma unroll
    for (int hf = 0; hf < 4; ++hf)
        #pragma unroll
        for (int r = 0; r < 4; ++r) {
            int q = q0 + 16 * w + 4 * lg + r;
            dst[(bT + q) * 64 + 16 * hf + l15] = oacc[hf][r];
        }
}

// ---------------------------------------------------------------------------
// Kernel 5: out += Op1 (deterministic k-split combine)
// ---------------------------------------------------------------------------
__global__ __launch_bounds__(256) void combine_kernel(
    float* __restrict__ out, const float* __restrict__ Op1)
{
    size_t idx = ((size_t)blockIdx.x * 256 + threadIdx.x) * 4;
    float4 a = *reinterpret_cast<const float4*>(out + idx);
    float4 c = *reinterpret_cast<const float4*>(Op1 + idx);
    *reinterpret_cast<float4*>(out + idx) =
        make_float4(a.x + c.x, a.y + c.y, a.z + c.z, a.w + c.w);
}

extern "C" void kernel_launch(void* const* d_in, const int* in_sizes, int n_in,
                              void* d_out, int out_size, void* d_ws, size_t ws_size,
                              hipStream_t stream) {
    (void)in_sizes; (void)n_in; (void)out_size; (void)ws_size;
    const float* x  = (const float*)d_in[0];
    const float* Wk = (const float*)d_in[1];
    const float* Wq = (const float*)d_in[2];
    const float* Wv = (const float*)d_in[3];
    float* out = (float*)d_out;
    char* w8 = (char*)d_ws;

    const size_t SZ = (size_t)NB * T_SEQ * CHEAD * sizeof(short);  // 4 MB
    short* Qhi  = (short*)(w8);
    short* Qlo  = (short*)(w8 + SZ);
    short* Khi  = (short*)(w8 + 2 * SZ);
    short* Klo  = (short*)(w8 + 3 * SZ);
    short* VThi = (short*)(w8 + 4 * SZ);
    short* VTlo = (short*)(w8 + 5 * SZ);
    short* Wp   = (short*)(w8 + 6 * SZ);                   // 786,432 B
    float* Dp   = (float*)(w8 + 6 * SZ + 786432);          // 524,288 B
    float* Dinv = (float*)(w8 + 6 * SZ + 786432 + 524288); // 131,072 B
    float* Op1  = (float*)(w8 + 6 * SZ + 786432 + 524288 + 131072);  // 8 MB
    // total ws use ≈ 33.4 MB (fits: round 1 used 42.5 MB successfully)

    hipLaunchKernelGGL(wsplit_kernel, dim3(768), dim3(256), 0, stream,
                       Wk, Wq, Wv, Wp);
    hipLaunchKernelGGL(proj_kernel, dim3(512), dim3(256), 0, stream,
                       x, Wp, Qhi, Qlo, Khi, Klo, VThi, VTlo);
    hipLaunchKernelGGL(colsum_kernel, dim3(64, 4, NB), dim3(256), 0, stream,
                       Qhi, Khi, Dp);
    hipLaunchKernelGGL(dinv_kernel, dim3(128), dim3(256), 0, stream,
                       Dp, Dinv);
    hipLaunchKernelGGL(out_kernel, dim3(1024), dim3(256), 0, stream,
                       Qhi, Qlo, Khi, Klo, VThi, VTlo, Dinv, out, Op1);
    hipLaunchKernelGGL(combine_kernel, dim3(2048), dim3(256), 0, stream,
                       out, Op1);
}